// Round 1
// baseline (2705.413 us; speedup 1.0000x reference)
//
#include <hip/hip_runtime.h>
#include <hip/hip_bf16.h>

#define NNODE 50000
#define NEDGE 640000
#define NREL  3
#define HIDD  128
#define GNUM  512
#define K1    112   // layer-1 GEMM K (99 used + 13 zero pad)
#define K2    512   // layer-2 GEMM K (3*128 relations + 128 root)

// ---------------- builders ----------------
__global__ void build_tabs_kernel(const float* __restrict__ shape_w,
                                  const float* __restrict__ color_w,
                                  const float* __restrict__ W1,
                                  const float* __restrict__ root1,
                                  float* __restrict__ B1eff,
                                  float* __restrict__ rootTab) {
    int idx = blockIdx.x * blockDim.x + threadIdx.x;
    if (idx >= 4 * 33 * 128) return;
    int h  = idx & 127;
    int j  = (idx >> 7) % 33;
    int rr = idx / (33 * 128);
    const float* Wsrc = (rr < 3) ? (W1 + (size_t)rr * 129 * 128) : root1; // [129][128]
    float v = 0.f;
    if (j < 16) {
        for (int e = 0; e < 64; ++e) v += shape_w[j * 64 + e] * Wsrc[e * 128 + h];
    } else if (j < 32) {
        int c = j - 16;
        for (int e = 0; e < 64; ++e) v += color_w[c * 64 + e] * Wsrc[(64 + e) * 128 + h];
    } else {
        v = Wsrc[128 * 128 + h];
    }
    if (rr < 3) B1eff[(rr * 33 + j) * 128 + h] = v;
    else        rootTab[j * 128 + h] = v;
}

__global__ void build_B2_kernel(const float* __restrict__ W2,
                                const float* __restrict__ root2,
                                float* __restrict__ B2) {
    int idx = blockIdx.x * blockDim.x + threadIdx.x; // 512*128
    if (idx >= K2 * 128) return;
    int k = idx >> 7;
    B2[idx] = (k < 384) ? W2[idx] : root2[idx - 384 * 128];
}

// ---------------- layer-1 scatter: 3 atomics/edge + count ----------------
__global__ void scatter1_kernel(const int* __restrict__ ei, const int* __restrict__ et,
                                const int* __restrict__ shape_id, const int* __restrict__ color_id,
                                const float* __restrict__ pos,
                                float* __restrict__ A1, float* __restrict__ cnt) {
    int e = blockIdx.x * blockDim.x + threadIdx.x;
    if (e >= NEDGE) return;
    int s = ei[e], d = ei[NEDGE + e], r = et[e];
    float* base = A1 + (size_t)d * K1 + r * 33;
    atomicAdd(base + shape_id[s], 1.f);
    atomicAdd(base + 16 + color_id[s], 1.f);
    atomicAdd(base + 32, pos[s]);
    atomicAdd(cnt + d * 3 + r, 1.f);
}

__global__ void rcnt_kernel(const float* __restrict__ cnt, float* __restrict__ rcnt) {
    int n = blockIdx.x * blockDim.x + threadIdx.x;
    if (n >= NNODE) return;
#pragma unroll
    for (int r = 0; r < 3; ++r) rcnt[n * 4 + r] = 1.f / fmaxf(cnt[n * 3 + r], 1.f);
    rcnt[n * 4 + 3] = 1.f;
}

// ---------------- layer-2 scatter: wave handles 4 edges, 16 lanes x 8 cols ----------------
__global__ void scatter2_kernel(const int* __restrict__ ei, const int* __restrict__ et,
                                float* __restrict__ A2) {
    int lane = threadIdx.x & 63;
    int wid  = blockIdx.x * 4 + (threadIdx.x >> 6);
    int e = wid * 4 + (lane >> 4);
    if (e >= NEDGE) return;
    int s = ei[e], d = ei[NEDGE + e], r = et[e];
    int j = (lane & 15) * 8;
    const float* xs = &A2[(size_t)s * 512 + 384 + j];   // x1 lives in A2 root block
    float4 v0 = *(const float4*)(xs);
    float4 v1 = *(const float4*)(xs + 4);
    float* out = &A2[(size_t)d * 512 + r * 128 + j];
    atomicAdd(out + 0, v0.x);
    atomicAdd(out + 1, v0.y);
    atomicAdd(out + 2, v0.z);
    atomicAdd(out + 3, v0.w);
    atomicAdd(out + 4, v1.x);
    atomicAdd(out + 5, v1.y);
    atomicAdd(out + 6, v1.z);
    atomicAdd(out + 7, v1.w);
}

// ---------------- fused GEMM (fp32, 64x128 tile, 4x8 microtile) ----------------
// MODE 1: A=[N,112] raw sums (scaled by rcnt on load, r=k/33), epilogue adds
//         root lookups + b1, relu, writes into A2 root block (stride 512).
// MODE 2: A=[N,512] (scaled by rcnt, r=k>>7; root block r=3 -> 1.0), epilogue
//         adds b2, relu, writes x2 (stride 128).
template<int MODE>
__global__ __launch_bounds__(256) void gemm_fused_kernel(
    const float* __restrict__ A, const float* __restrict__ B,
    const float* __restrict__ rcnt,
    const int* __restrict__ shape_id, const int* __restrict__ color_id,
    const float* __restrict__ pos, const float* __restrict__ rootTab,
    const float* __restrict__ bias,
    float* __restrict__ Cout) {
    constexpr int K  = (MODE == 1) ? K1 : K2;
    constexpr int BM = 64, BK = 16;
    __shared__ float As[BK][BM + 4];   // transposed A tile (pad 4: 2-way max on write)
    __shared__ float Bs[BK][HIDD];
    const int t  = threadIdx.x;
    const int m0 = blockIdx.x * BM;
    const int tx = t & 15, ty = t >> 4;
    const int arow = t >> 2, ac4 = (t & 3) * 4;
    const int brow = t >> 4, bc = (t & 15) * 8;
    float acc[4][8] = {};
    for (int kt = 0; kt < K; kt += BK) {
        { // A tile: load float4, scale by 1/max(cnt,1), store transposed
            int gr = m0 + arow;
            float4 v = make_float4(0.f, 0.f, 0.f, 0.f);
            if (gr < NNODE) {
                v = *(const float4*)&A[(size_t)gr * K + kt + ac4];
                float* vp = &v.x;
#pragma unroll
                for (int i = 0; i < 4; ++i) {
                    int kk = kt + ac4 + i;
                    int r = (MODE == 1) ? min(kk / 33, 3) : (kk >> 7);
                    vp[i] *= rcnt[gr * 4 + r];
                }
            }
            As[ac4 + 0][arow] = v.x;
            As[ac4 + 1][arow] = v.y;
            As[ac4 + 2][arow] = v.z;
            As[ac4 + 3][arow] = v.w;
        }
        { // B tile
            const float4* src = (const float4*)&B[(size_t)(kt + brow) * HIDD + bc];
            *(float4*)&Bs[brow][bc]     = src[0];
            *(float4*)&Bs[brow][bc + 4] = src[1];
        }
        __syncthreads();
#pragma unroll
        for (int k = 0; k < BK; ++k) {
            float a[4], b[8];
            *(float4*)a      = *(const float4*)&As[k][ty * 4];
            *(float4*)&b[0]  = *(const float4*)&Bs[k][tx * 8];
            *(float4*)&b[4]  = *(const float4*)&Bs[k][tx * 8 + 4];
#pragma unroll
            for (int i = 0; i < 4; ++i)
#pragma unroll
                for (int j = 0; j < 8; ++j)
                    acc[i][j] = fmaf(a[i], b[j], acc[i][j]);
        }
        __syncthreads();
    }
#pragma unroll
    for (int i = 0; i < 4; ++i) {
        int gr = m0 + ty * 4 + i;
        if (gr >= NNODE) continue;
        if constexpr (MODE == 1) {
            int sid = shape_id[gr], cid = color_id[gr];
            float p = pos[gr];
#pragma unroll
            for (int j = 0; j < 8; ++j) {
                int h = tx * 8 + j;
                float v = acc[i][j] + rootTab[sid * 128 + h] + rootTab[(16 + cid) * 128 + h]
                        + p * rootTab[32 * 128 + h] + bias[h];
                Cout[(size_t)gr * 512 + 384 + h] = fmaxf(v, 0.f);
            }
        } else {
#pragma unroll
            for (int j = 0; j < 8; ++j) {
                int h = tx * 8 + j;
                float v = acc[i][j] + bias[h];
                Cout[(size_t)gr * HIDD + h] = fmaxf(v, 0.f);
            }
        }
    }
}

// ---------------- pooling (batch is sorted -> run-length reduce) ----------------
__global__ void pool_kernel(const float* __restrict__ x2, const int* __restrict__ batch,
                            float* __restrict__ pooled, float* __restrict__ cntg) {
    const int CH = 512;
    int h  = threadIdx.x; // 128
    int n0 = blockIdx.x * CH;
    if (n0 >= NNODE) return;
    int n1 = min(n0 + CH, NNODE);
    int cur = batch[n0];
    float acc = 0.f;
    int run = 0;
    for (int n = n0; n < n1; ++n) {
        int g = batch[n];
        if (g != cur) {
            atomicAdd(&pooled[cur * 128 + h], acc);
            if (h == 0) atomicAdd(&cntg[cur], (float)run);
            acc = 0.f; run = 0; cur = g;
        }
        acc += x2[(size_t)n * 128 + h];
        ++run;
    }
    atomicAdd(&pooled[cur * 128 + h], acc);
    if (h == 0) atomicAdd(&cntg[cur], (float)run);
}

__global__ void final_kernel(const float* __restrict__ pooled, const float* __restrict__ cntg,
                             const float* __restrict__ lin_w, const float* __restrict__ lin_b,
                             float* __restrict__ out) {
    int idx = blockIdx.x * blockDim.x + threadIdx.x;
    if (idx >= GNUM * 4) return;
    int g = idx >> 2, c = idx & 3;
    float dot = 0.f;
    for (int k = 0; k < 128; ++k) dot += pooled[g * 128 + k] * lin_w[k * 4 + c];
    out[idx] = dot / fmaxf(cntg[g], 1.f) + lin_b[c];
}

// ---------------- launch ----------------
extern "C" void kernel_launch(void* const* d_in, const int* in_sizes, int n_in,
                              void* d_out, int out_size, void* d_ws, size_t ws_size,
                              hipStream_t stream) {
    const float* pos      = (const float*)d_in[0];
    const int*   shape_id = (const int*)d_in[1];
    const int*   color_id = (const int*)d_in[2];
    const int*   ei       = (const int*)d_in[3];
    const int*   et       = (const int*)d_in[4];
    const int*   batch    = (const int*)d_in[5];
    const float* shape_w  = (const float*)d_in[6];
    const float* color_w  = (const float*)d_in[7];
    const float* W1       = (const float*)d_in[8];
    const float* root1    = (const float*)d_in[9];
    const float* b1       = (const float*)d_in[10];
    const float* W2       = (const float*)d_in[11];
    const float* root2    = (const float*)d_in[12];
    const float* b2       = (const float*)d_in[13];
    const float* lin_w    = (const float*)d_in[14];
    const float* lin_b    = (const float*)d_in[15];
    float* out = (float*)d_out;

    char* p = (char*)d_ws;
    auto alloc = [&](size_t bytes) { char* r = p; p += (bytes + 255) & ~(size_t)255; return r; };
    float* cnt     = (float*)alloc((size_t)NNODE * 3 * 4);
    float* A1      = (float*)alloc((size_t)NNODE * K1 * 4);
    float* rcntBuf = (float*)alloc((size_t)NNODE * 4 * 4);
    float* A2      = (float*)alloc((size_t)NNODE * 512 * 4);
    float* x2      = (float*)alloc((size_t)NNODE * 128 * 4);
    float* B1eff   = (float*)alloc((size_t)K1 * 128 * 4);
    float* rootTab = (float*)alloc((size_t)33 * 128 * 4);
    float* B2      = (float*)alloc((size_t)K2 * 128 * 4);
    float* pooled  = (float*)alloc((size_t)GNUM * 128 * 4);
    float* cntg    = (float*)alloc((size_t)GNUM * 4);

    // zero accumulation buffers (must happen every call - deterministic)
    hipMemsetAsync(cnt,    0, (size_t)NNODE * 3 * 4, stream);
    hipMemsetAsync(A1,     0, (size_t)NNODE * K1 * 4, stream);
    hipMemsetAsync(A2,     0, (size_t)NNODE * 512 * 4, stream);
    hipMemsetAsync(B1eff,  0, (size_t)K1 * 128 * 4, stream);
    hipMemsetAsync(pooled, 0, (size_t)GNUM * 128 * 4, stream);
    hipMemsetAsync(cntg,   0, (size_t)GNUM * 4, stream);

    build_tabs_kernel<<<(4 * 33 * 128 + 255) / 256, 256, 0, stream>>>(
        shape_w, color_w, W1, root1, B1eff, rootTab);
    build_B2_kernel<<<(K2 * 128 + 255) / 256, 256, 0, stream>>>(W2, root2, B2);

    scatter1_kernel<<<(NEDGE + 255) / 256, 256, 0, stream>>>(
        ei, et, shape_id, color_id, pos, A1, cnt);
    rcnt_kernel<<<(NNODE + 255) / 256, 256, 0, stream>>>(cnt, rcntBuf);

    gemm_fused_kernel<1><<<(NNODE + 63) / 64, 256, 0, stream>>>(
        A1, B1eff, rcntBuf, shape_id, color_id, pos, rootTab, b1, A2);

    scatter2_kernel<<<(NEDGE + 15) / 16, 256, 0, stream>>>(ei, et, A2);

    gemm_fused_kernel<2><<<(NNODE + 63) / 64, 256, 0, stream>>>(
        A2, B2, rcntBuf, nullptr, nullptr, nullptr, nullptr, b2, x2);

    pool_kernel<<<(NNODE + 511) / 512, 128, 0, stream>>>(x2, batch, pooled, cntg);

    final_kernel<<<(GNUM * 4 + 255) / 256, 256, 0, stream>>>(
        pooled, cntg, lin_w, lin_b, out);
}

// Round 2
// 563.294 us; speedup vs baseline: 4.8028x; 4.8028x over previous
//
#include <hip/hip_runtime.h>
#include <hip/hip_bf16.h>

#define NNODE 50000
#define NEDGE 640000
#define NREL  3
#define HIDD  128
#define GNUM  512
#define K1    112   // layer-1 GEMM K (99 used + 13 zero pad)
#define K2    512   // layer-2 GEMM K (3*128 relations + 128 root)
#define NB    196   // scan blocks = ceil(NNODE/256)

// ---------------- builders ----------------
__global__ void build_tabs_kernel(const float* __restrict__ shape_w,
                                  const float* __restrict__ color_w,
                                  const float* __restrict__ W1,
                                  const float* __restrict__ root1,
                                  float* __restrict__ B1eff,
                                  float* __restrict__ rootTab) {
    int idx = blockIdx.x * blockDim.x + threadIdx.x;
    if (idx >= 4 * 33 * 128) return;
    int h  = idx & 127;
    int j  = (idx >> 7) % 33;
    int rr = idx / (33 * 128);
    const float* Wsrc = (rr < 3) ? (W1 + (size_t)rr * 129 * 128) : root1; // [129][128]
    float v = 0.f;
    if (j < 16) {
        for (int e = 0; e < 64; ++e) v += shape_w[j * 64 + e] * Wsrc[e * 128 + h];
    } else if (j < 32) {
        int c = j - 16;
        for (int e = 0; e < 64; ++e) v += color_w[c * 64 + e] * Wsrc[(64 + e) * 128 + h];
    } else {
        v = Wsrc[128 * 128 + h];
    }
    if (rr < 3) B1eff[(rr * 33 + j) * 128 + h] = v;
    else        rootTab[j * 128 + h] = v;
}

__global__ void build_B2_kernel(const float* __restrict__ W2,
                                const float* __restrict__ root2,
                                float* __restrict__ B2) {
    int idx = blockIdx.x * blockDim.x + threadIdx.x; // 512*128
    if (idx >= K2 * 128) return;
    int k = idx >> 7;
    B2[idx] = (k < 384) ? W2[idx] : root2[idx - 384 * 128];
}

// ---------------- edge counting: 1 int atomic/edge ----------------
__global__ void count_kernel(const int* __restrict__ ei, const int* __restrict__ et,
                             int* __restrict__ cnt) {
    int e = blockIdx.x * blockDim.x + threadIdx.x;
    if (e >= NEDGE) return;
    int d = ei[NEDGE + e], r = et[e];
    atomicAdd(&cnt[d * 3 + r], 1);
}

// ---------------- prefix scan over per-node degree (3-phase) ----------------
__global__ void scan_partial_kernel(const int* __restrict__ cnt, int* __restrict__ partial) {
    __shared__ int sh[256];
    int t = threadIdx.x, i = blockIdx.x * 256 + t;
    int v = (i < NNODE) ? cnt[3 * i] + cnt[3 * i + 1] + cnt[3 * i + 2] : 0;
    sh[t] = v; __syncthreads();
    for (int o = 128; o > 0; o >>= 1) { if (t < o) sh[t] += sh[t + o]; __syncthreads(); }
    if (t == 0) partial[blockIdx.x] = sh[0];
}

__global__ void scan_mid_kernel(const int* __restrict__ partial, int* __restrict__ partial_pre,
                                int* __restrict__ offs) {
    __shared__ int sh[256];
    int t = threadIdx.x;
    int v = (t < NB) ? partial[t] : 0;
    sh[t] = v; __syncthreads();
    for (int o = 1; o < 256; o <<= 1) {
        int x = (t >= o) ? sh[t - o] : 0; __syncthreads();
        sh[t] += x; __syncthreads();
    }
    if (t < NB) partial_pre[t] = sh[t] - v;
    if (t == 0) offs[NNODE] = NEDGE;
}

__global__ void scan_final_kernel(const int* __restrict__ cnt, const int* __restrict__ partial_pre,
                                  int* __restrict__ offs, int* __restrict__ cursor) {
    __shared__ int sh[256];
    int t = threadIdx.x, i = blockIdx.x * 256 + t;
    int v = (i < NNODE) ? cnt[3 * i] + cnt[3 * i + 1] + cnt[3 * i + 2] : 0;
    sh[t] = v; __syncthreads();
    for (int o = 1; o < 256; o <<= 1) {
        int x = (t >= o) ? sh[t - o] : 0; __syncthreads();
        sh[t] += x; __syncthreads();
    }
    int exc = sh[t] - v + partial_pre[blockIdx.x];
    if (i < NNODE) { offs[i] = exc; cursor[i] = exc; }
}

// ---------------- fill: dst-sorted edge list, src|rel packed ----------------
__global__ void fill_kernel(const int* __restrict__ ei, const int* __restrict__ et,
                            int* __restrict__ cursor, int* __restrict__ sorted) {
    int e = blockIdx.x * blockDim.x + threadIdx.x;
    if (e >= NEDGE) return;
    int s = ei[e], d = ei[NEDGE + e], r = et[e];
    int p = atomicAdd(&cursor[d], 1);
    sorted[p] = s | (r << 16);   // NNODE < 65536
}

// ---------------- layer-1 scatter: 3 atomics/edge ----------------
__global__ void scatter1_kernel(const int* __restrict__ ei, const int* __restrict__ et,
                                const int* __restrict__ shape_id, const int* __restrict__ color_id,
                                const float* __restrict__ pos,
                                float* __restrict__ A1) {
    int e = blockIdx.x * blockDim.x + threadIdx.x;
    if (e >= NEDGE) return;
    int s = ei[e], d = ei[NEDGE + e], r = et[e];
    float* base = A1 + (size_t)d * K1 + r * 33;
    atomicAdd(base + shape_id[s], 1.f);
    atomicAdd(base + 16 + color_id[s], 1.f);
    atomicAdd(base + 32, pos[s]);
}

__global__ void rcnt_kernel(const int* __restrict__ cnt, float* __restrict__ rcnt) {
    int n = blockIdx.x * blockDim.x + threadIdx.x;
    if (n >= NNODE) return;
#pragma unroll
    for (int r = 0; r < 3; ++r) rcnt[n * 4 + r] = 1.f / fmaxf((float)cnt[n * 3 + r], 1.f);
    rcnt[n * 4 + 3] = 1.f;
}

// ---------------- layer-2 aggregation: atomic-free CSR gather ----------------
// x1 lives in A2 cols [384,512) (written by gemm1). Writes cols [0,384) = per-rel means.
__global__ __launch_bounds__(128) void aggregate_kernel(const int* __restrict__ offs,
                                                        const int* __restrict__ sorted,
                                                        const float* __restrict__ rcnt,
                                                        float* __restrict__ A2) {
    int d = blockIdx.x, h = threadIdx.x;
    int beg = offs[d], end = offs[d + 1];
    __shared__ int pk[128];
    float a0 = 0.f, a1 = 0.f, a2 = 0.f;
    for (int base = beg; base < end; base += 128) {
        int m = min(128, end - base);
        __syncthreads();
        if (h < m) pk[h] = sorted[base + h];
        __syncthreads();
        for (int i = 0; i < m; ++i) {
            int v = pk[i];
            int s = v & 0xFFFF, r = v >> 16;
            float x = A2[(size_t)s * 512 + 384 + h];
            if (r == 0) a0 += x; else if (r == 1) a1 += x; else a2 += x;
        }
    }
    float* o = &A2[(size_t)d * 512 + h];
    o[0]   = a0 * rcnt[d * 4 + 0];
    o[128] = a1 * rcnt[d * 4 + 1];
    o[256] = a2 * rcnt[d * 4 + 2];
}

// ---------------- fused GEMM (fp32, 64x128 tile, 4x8 microtile) ----------------
// MODE 1: A=[N,112] raw sums (scaled by rcnt on load), epilogue adds root
//         lookups + b1, relu, writes into A2 root block (stride 512).
// MODE 2: A=[N,512] pre-scaled means, epilogue adds b2, relu, writes x2.
template<int MODE>
__global__ __launch_bounds__(256) void gemm_fused_kernel(
    const float* __restrict__ A, const float* __restrict__ B,
    const float* __restrict__ rcnt,
    const int* __restrict__ shape_id, const int* __restrict__ color_id,
    const float* __restrict__ pos, const float* __restrict__ rootTab,
    const float* __restrict__ bias,
    float* __restrict__ Cout) {
    constexpr int K  = (MODE == 1) ? K1 : K2;
    constexpr int BM = 64, BK = 16;
    __shared__ float As[BK][BM + 4];
    __shared__ float Bs[BK][HIDD];
    const int t  = threadIdx.x;
    const int m0 = blockIdx.x * BM;
    const int tx = t & 15, ty = t >> 4;
    const int arow = t >> 2, ac4 = (t & 3) * 4;
    const int brow = t >> 4, bc = (t & 15) * 8;
    float acc[4][8] = {};
    for (int kt = 0; kt < K; kt += BK) {
        { // A tile
            int gr = m0 + arow;
            float4 v = make_float4(0.f, 0.f, 0.f, 0.f);
            if (gr < NNODE) {
                v = *(const float4*)&A[(size_t)gr * K + kt + ac4];
                if constexpr (MODE == 1) {
                    float* vp = &v.x;
#pragma unroll
                    for (int i = 0; i < 4; ++i) {
                        int kk = kt + ac4 + i;
                        int r = min(kk / 33, 3);
                        vp[i] *= rcnt[gr * 4 + r];
                    }
                }
            }
            As[ac4 + 0][arow] = v.x;
            As[ac4 + 1][arow] = v.y;
            As[ac4 + 2][arow] = v.z;
            As[ac4 + 3][arow] = v.w;
        }
        { // B tile
            const float4* src = (const float4*)&B[(size_t)(kt + brow) * HIDD + bc];
            *(float4*)&Bs[brow][bc]     = src[0];
            *(float4*)&Bs[brow][bc + 4] = src[1];
        }
        __syncthreads();
#pragma unroll
        for (int k = 0; k < BK; ++k) {
            float a[4], b[8];
            *(float4*)a      = *(const float4*)&As[k][ty * 4];
            *(float4*)&b[0]  = *(const float4*)&Bs[k][tx * 8];
            *(float4*)&b[4]  = *(const float4*)&Bs[k][tx * 8 + 4];
#pragma unroll
            for (int i = 0; i < 4; ++i)
#pragma unroll
                for (int j = 0; j < 8; ++j)
                    acc[i][j] = fmaf(a[i], b[j], acc[i][j]);
        }
        __syncthreads();
    }
#pragma unroll
    for (int i = 0; i < 4; ++i) {
        int gr = m0 + ty * 4 + i;
        if (gr >= NNODE) continue;
        if constexpr (MODE == 1) {
            int sid = shape_id[gr], cid = color_id[gr];
            float p = pos[gr];
#pragma unroll
            for (int j = 0; j < 8; ++j) {
                int h = tx * 8 + j;
                float v = acc[i][j] + rootTab[sid * 128 + h] + rootTab[(16 + cid) * 128 + h]
                        + p * rootTab[32 * 128 + h] + bias[h];
                Cout[(size_t)gr * 512 + 384 + h] = fmaxf(v, 0.f);
            }
        } else {
#pragma unroll
            for (int j = 0; j < 8; ++j) {
                int h = tx * 8 + j;
                float v = acc[i][j] + bias[h];
                Cout[(size_t)gr * HIDD + h] = fmaxf(v, 0.f);
            }
        }
    }
}

// ---------------- pooling (batch is sorted -> run-length reduce) ----------------
__global__ void pool_kernel(const float* __restrict__ x2, const int* __restrict__ batch,
                            float* __restrict__ pooled, float* __restrict__ cntg) {
    const int CH = 512;
    int h  = threadIdx.x; // 128
    int n0 = blockIdx.x * CH;
    if (n0 >= NNODE) return;
    int n1 = min(n0 + CH, NNODE);
    int cur = batch[n0];
    float acc = 0.f;
    int run = 0;
    for (int n = n0; n < n1; ++n) {
        int g = batch[n];
        if (g != cur) {
            atomicAdd(&pooled[cur * 128 + h], acc);
            if (h == 0) atomicAdd(&cntg[cur], (float)run);
            acc = 0.f; run = 0; cur = g;
        }
        acc += x2[(size_t)n * 128 + h];
        ++run;
    }
    atomicAdd(&pooled[cur * 128 + h], acc);
    if (h == 0) atomicAdd(&cntg[cur], (float)run);
}

__global__ void final_kernel(const float* __restrict__ pooled, const float* __restrict__ cntg,
                             const float* __restrict__ lin_w, const float* __restrict__ lin_b,
                             float* __restrict__ out) {
    int idx = blockIdx.x * blockDim.x + threadIdx.x;
    if (idx >= GNUM * 4) return;
    int g = idx >> 2, c = idx & 3;
    float dot = 0.f;
    for (int k = 0; k < 128; ++k) dot += pooled[g * 128 + k] * lin_w[k * 4 + c];
    out[idx] = dot / fmaxf(cntg[g], 1.f) + lin_b[c];
}

// ---------------- launch ----------------
extern "C" void kernel_launch(void* const* d_in, const int* in_sizes, int n_in,
                              void* d_out, int out_size, void* d_ws, size_t ws_size,
                              hipStream_t stream) {
    const float* pos      = (const float*)d_in[0];
    const int*   shape_id = (const int*)d_in[1];
    const int*   color_id = (const int*)d_in[2];
    const int*   ei       = (const int*)d_in[3];
    const int*   et       = (const int*)d_in[4];
    const int*   batch    = (const int*)d_in[5];
    const float* shape_w  = (const float*)d_in[6];
    const float* color_w  = (const float*)d_in[7];
    const float* W1       = (const float*)d_in[8];
    const float* root1    = (const float*)d_in[9];
    const float* b1       = (const float*)d_in[10];
    const float* W2       = (const float*)d_in[11];
    const float* root2    = (const float*)d_in[12];
    const float* b2       = (const float*)d_in[13];
    const float* lin_w    = (const float*)d_in[14];
    const float* lin_b    = (const float*)d_in[15];
    float* out = (float*)d_out;

    char* p = (char*)d_ws;
    auto alloc = [&](size_t bytes) { char* r = p; p += (bytes + 255) & ~(size_t)255; return r; };
    int*   cnt     = (int*)alloc((size_t)NNODE * 3 * 4);
    float* A1      = (float*)alloc((size_t)NNODE * K1 * 4);
    float* rcntBuf = (float*)alloc((size_t)NNODE * 4 * 4);
    float* A2      = (float*)alloc((size_t)NNODE * 512 * 4);
    float* x2      = (float*)alloc((size_t)NNODE * 128 * 4);
    float* B1eff   = (float*)alloc((size_t)K1 * 128 * 4);
    float* rootTab = (float*)alloc((size_t)33 * 128 * 4);
    float* B2      = (float*)alloc((size_t)K2 * 128 * 4);
    float* pooled  = (float*)alloc((size_t)GNUM * 128 * 4);
    float* cntg    = (float*)alloc((size_t)GNUM * 4);
    // CSR temporaries alias into x2 (all consumed before gemm2 writes x2)
    char* xb = (char*)x2;
    int* sorted     = (int*)(xb);                       // E ints   = 2.56 MB
    int* offs       = (int*)(xb + 2600960);             // NNODE+1 ints
    int* cursor     = (int*)(xb + 2900992);             // NNODE ints
    int* partial    = (int*)(xb + 3200000);             // NB ints
    int* partialPre = (int*)(xb + 3210240);             // NB ints

    hipMemsetAsync(cnt,    0, (size_t)NNODE * 3 * 4, stream);
    hipMemsetAsync(A1,     0, (size_t)NNODE * K1 * 4, stream);
    hipMemsetAsync(pooled, 0, (size_t)GNUM * 128 * 4, stream);
    hipMemsetAsync(cntg,   0, (size_t)GNUM * 4, stream);

    build_tabs_kernel<<<(4 * 33 * 128 + 255) / 256, 256, 0, stream>>>(
        shape_w, color_w, W1, root1, B1eff, rootTab);
    build_B2_kernel<<<(K2 * 128 + 255) / 256, 256, 0, stream>>>(W2, root2, B2);

    count_kernel<<<(NEDGE + 255) / 256, 256, 0, stream>>>(ei, et, cnt);
    scan_partial_kernel<<<NB, 256, 0, stream>>>(cnt, partial);
    scan_mid_kernel<<<1, 256, 0, stream>>>(partial, partialPre, offs);
    scan_final_kernel<<<NB, 256, 0, stream>>>(cnt, partialPre, offs, cursor);
    fill_kernel<<<(NEDGE + 255) / 256, 256, 0, stream>>>(ei, et, cursor, sorted);
    rcnt_kernel<<<(NNODE + 255) / 256, 256, 0, stream>>>(cnt, rcntBuf);

    scatter1_kernel<<<(NEDGE + 255) / 256, 256, 0, stream>>>(
        ei, et, shape_id, color_id, pos, A1);

    gemm_fused_kernel<1><<<(NNODE + 63) / 64, 256, 0, stream>>>(
        A1, B1eff, rcntBuf, shape_id, color_id, pos, rootTab, b1, A2);

    aggregate_kernel<<<NNODE, 128, 0, stream>>>(offs, sorted, rcntBuf, A2);

    gemm_fused_kernel<2><<<(NNODE + 63) / 64, 256, 0, stream>>>(
        A2, B2, nullptr, nullptr, nullptr, nullptr, nullptr, b2, x2);

    pool_kernel<<<(NNODE + 511) / 512, 128, 0, stream>>>(x2, batch, pooled, cntg);

    final_kernel<<<(GNUM * 4 + 255) / 256, 256, 0, stream>>>(
        pooled, cntg, lin_w, lin_b, out);
}

// Round 3
// 307.021 us; speedup vs baseline: 8.8118x; 1.8347x over previous
//
#include <hip/hip_runtime.h>
#include <hip/hip_bf16.h>

#define NNODE 50000
#define NEDGE 640000
#define NREL  3
#define HIDD  128
#define GNUM  512
#define K1    112   // layer-1 GEMM K (99 used + 13 zero pad)
#define K2    512   // layer-2 GEMM K (3*128 relations + 128 root)
#define NB    196   // scan blocks = ceil(NNODE/256)

typedef float  f32x4   __attribute__((ext_vector_type(4)));
typedef short  vshort8 __attribute__((ext_vector_type(8)));
typedef short  vshort4 __attribute__((ext_vector_type(4)));

// ---------------- builders ----------------
__global__ void build_tabs_kernel(const float* __restrict__ shape_w,
                                  const float* __restrict__ color_w,
                                  const float* __restrict__ W1,
                                  const float* __restrict__ root1,
                                  float* __restrict__ B1eff,
                                  float* __restrict__ rootTab) {
    int idx = blockIdx.x * blockDim.x + threadIdx.x;
    if (idx >= 4 * 33 * 128) return;
    int h  = idx & 127;
    int j  = (idx >> 7) % 33;
    int rr = idx / (33 * 128);
    const float* Wsrc = (rr < 3) ? (W1 + (size_t)rr * 129 * 128) : root1; // [129][128]
    float v = 0.f;
    if (j < 16) {
        for (int e = 0; e < 64; ++e) v += shape_w[j * 64 + e] * Wsrc[e * 128 + h];
    } else if (j < 32) {
        int c = j - 16;
        for (int e = 0; e < 64; ++e) v += color_w[c * 64 + e] * Wsrc[(64 + e) * 128 + h];
    } else {
        v = Wsrc[128 * 128 + h];
    }
    if (rr < 3) B1eff[(rr * 33 + j) * 128 + h] = v;
    else        rootTab[j * 128 + h] = v;
}

__device__ __forceinline__ void split_bf16(float f, short& hi, short& lo) {
    unsigned u  = __float_as_uint(f);
    unsigned uh = (u + 0x7FFFu + ((u >> 16) & 1u)) >> 16;
    hi = (short)uh;
    float fl = f - __uint_as_float(uh << 16);
    unsigned ul  = __float_as_uint(fl);
    unsigned ulh = (ul + 0x7FFFu + ((ul >> 16) & 1u)) >> 16;
    lo = (short)ulh;
}

// B2 transposed + split: Bt[n][k], k<384 -> W2, else root2
__global__ void build_B2t_kernel(const float* __restrict__ W2,
                                 const float* __restrict__ root2,
                                 short* __restrict__ Bt_hi,
                                 short* __restrict__ Bt_lo) {
    int idx = blockIdx.x * blockDim.x + threadIdx.x; // 512*128
    if (idx >= K2 * 128) return;
    int k = idx >> 7, n = idx & 127;
    float v = (k < 384) ? W2[idx] : root2[idx - 384 * 128];
    short h, l;
    split_bf16(v, h, l);
    Bt_hi[(size_t)n * K2 + k] = h;
    Bt_lo[(size_t)n * K2 + k] = l;
}

// ---------------- edge counting: 1 int atomic/edge ----------------
__global__ void count_kernel(const int* __restrict__ ei, const int* __restrict__ et,
                             int* __restrict__ cnt) {
    int e = blockIdx.x * blockDim.x + threadIdx.x;
    if (e >= NEDGE) return;
    int d = ei[NEDGE + e], r = et[e];
    atomicAdd(&cnt[d * 3 + r], 1);
}

// ---------------- prefix scan over per-node degree (3-phase) ----------------
__global__ void scan_partial_kernel(const int* __restrict__ cnt, int* __restrict__ partial) {
    __shared__ int sh[256];
    int t = threadIdx.x, i = blockIdx.x * 256 + t;
    int v = (i < NNODE) ? cnt[3 * i] + cnt[3 * i + 1] + cnt[3 * i + 2] : 0;
    sh[t] = v; __syncthreads();
    for (int o = 128; o > 0; o >>= 1) { if (t < o) sh[t] += sh[t + o]; __syncthreads(); }
    if (t == 0) partial[blockIdx.x] = sh[0];
}

__global__ void scan_mid_kernel(const int* __restrict__ partial, int* __restrict__ partial_pre,
                                int* __restrict__ offs) {
    __shared__ int sh[256];
    int t = threadIdx.x;
    int v = (t < NB) ? partial[t] : 0;
    sh[t] = v; __syncthreads();
    for (int o = 1; o < 256; o <<= 1) {
        int x = (t >= o) ? sh[t - o] : 0; __syncthreads();
        sh[t] += x; __syncthreads();
    }
    if (t < NB) partial_pre[t] = sh[t] - v;
    if (t == 0) offs[NNODE] = NEDGE;
}

__global__ void scan_final_kernel(const int* __restrict__ cnt, const int* __restrict__ partial_pre,
                                  int* __restrict__ offs, int* __restrict__ cursor) {
    __shared__ int sh[256];
    int t = threadIdx.x, i = blockIdx.x * 256 + t;
    int v = (i < NNODE) ? cnt[3 * i] + cnt[3 * i + 1] + cnt[3 * i + 2] : 0;
    sh[t] = v; __syncthreads();
    for (int o = 1; o < 256; o <<= 1) {
        int x = (t >= o) ? sh[t - o] : 0; __syncthreads();
        sh[t] += x; __syncthreads();
    }
    int exc = sh[t] - v + partial_pre[blockIdx.x];
    if (i < NNODE) { offs[i] = exc; cursor[i] = exc; }
}

// ---------------- fill: dst-sorted edge list, src|rel packed ----------------
__global__ void fill_kernel(const int* __restrict__ ei, const int* __restrict__ et,
                            int* __restrict__ cursor, int* __restrict__ sorted) {
    int e = blockIdx.x * blockDim.x + threadIdx.x;
    if (e >= NEDGE) return;
    int s = ei[e], d = ei[NEDGE + e], r = et[e];
    int p = atomicAdd(&cursor[d], 1);
    sorted[p] = s | (r << 16);   // NNODE < 65536
}

// ---------------- layer-1 histogram via CSR (no global atomics) ----------------
__global__ __launch_bounds__(64) void hist1_kernel(const int* __restrict__ offs,
                                                   const int* __restrict__ sorted,
                                                   const int* __restrict__ shape_id,
                                                   const int* __restrict__ color_id,
                                                   const float* __restrict__ pos,
                                                   float* __restrict__ A1) {
    int d = blockIdx.x, t = threadIdx.x;
    __shared__ float hist[3][34];
    float* hf = &hist[0][0];
    for (int i = t; i < 102; i += 64) hf[i] = 0.f;
    __syncthreads();
    int beg = offs[d], end = offs[d + 1];
    for (int i = beg + t; i < end; i += 64) {
        int v = sorted[i];
        int s = v & 0xFFFF, r = v >> 16;
        atomicAdd(&hist[r][shape_id[s]], 1.f);
        atomicAdd(&hist[r][16 + color_id[s]], 1.f);
        atomicAdd(&hist[r][32], pos[s]);
    }
    __syncthreads();
    for (int i = t; i < K1; i += 64)
        A1[(size_t)d * K1 + i] = (i < 99) ? hf[(i / 33) * 34 + (i % 33)] : 0.f;
}

__global__ void rcnt_kernel(const int* __restrict__ cnt, float* __restrict__ rcnt) {
    int n = blockIdx.x * blockDim.x + threadIdx.x;
    if (n >= NNODE) return;
#pragma unroll
    for (int r = 0; r < 3; ++r) rcnt[n * 4 + r] = 1.f / fmaxf((float)cnt[n * 3 + r], 1.f);
    rcnt[n * 4 + 3] = 1.f;
}

// ---------------- layer-2 aggregation: atomic-free CSR gather ----------------
__global__ __launch_bounds__(128) void aggregate_kernel(const int* __restrict__ offs,
                                                        const int* __restrict__ sorted,
                                                        const float* __restrict__ rcnt,
                                                        float* __restrict__ A2) {
    int d = blockIdx.x, h = threadIdx.x;
    int beg = offs[d], end = offs[d + 1];
    __shared__ int pk[128];
    float a0 = 0.f, a1 = 0.f, a2 = 0.f;
    for (int base = beg; base < end; base += 128) {
        int m = min(128, end - base);
        __syncthreads();
        if (h < m) pk[h] = sorted[base + h];
        __syncthreads();
        for (int i = 0; i < m; ++i) {
            int v = pk[i];
            int s = v & 0xFFFF, r = v >> 16;
            float x = A2[(size_t)s * 512 + 384 + h];
            if (r == 0) a0 += x; else if (r == 1) a1 += x; else a2 += x;
        }
    }
    float* o = &A2[(size_t)d * 512 + h];
    o[0]   = a0 * rcnt[d * 4 + 0];
    o[128] = a1 * rcnt[d * 4 + 1];
    o[256] = a2 * rcnt[d * 4 + 2];
}

// ---------------- layer-1 fused GEMM (fp32, 64x128 tile, 4x8 microtile) ----------------
__global__ __launch_bounds__(256) void gemm1_kernel(
    const float* __restrict__ A, const float* __restrict__ B,
    const float* __restrict__ rcnt,
    const int* __restrict__ shape_id, const int* __restrict__ color_id,
    const float* __restrict__ pos, const float* __restrict__ rootTab,
    const float* __restrict__ bias,
    float* __restrict__ Cout) {
    constexpr int K = K1, BM = 64, BK = 16;
    __shared__ float As[BK][BM + 4];
    __shared__ float Bs[BK][HIDD];
    const int t  = threadIdx.x;
    const int m0 = blockIdx.x * BM;
    const int tx = t & 15, ty = t >> 4;
    const int arow = t >> 2, ac4 = (t & 3) * 4;
    const int brow = t >> 4, bc = (t & 15) * 8;
    float acc[4][8] = {};
    for (int kt = 0; kt < K; kt += BK) {
        {
            int gr = m0 + arow;
            float4 v = make_float4(0.f, 0.f, 0.f, 0.f);
            if (gr < NNODE) {
                v = *(const float4*)&A[(size_t)gr * K + kt + ac4];
                float* vp = &v.x;
#pragma unroll
                for (int i = 0; i < 4; ++i) {
                    int kk = kt + ac4 + i;
                    int r = min(kk / 33, 3);
                    vp[i] *= rcnt[gr * 4 + r];
                }
            }
            As[ac4 + 0][arow] = v.x;
            As[ac4 + 1][arow] = v.y;
            As[ac4 + 2][arow] = v.z;
            As[ac4 + 3][arow] = v.w;
        }
        {
            const float4* src = (const float4*)&B[(size_t)(kt + brow) * HIDD + bc];
            *(float4*)&Bs[brow][bc]     = src[0];
            *(float4*)&Bs[brow][bc + 4] = src[1];
        }
        __syncthreads();
#pragma unroll
        for (int k = 0; k < BK; ++k) {
            float a[4], b[8];
            *(float4*)a      = *(const float4*)&As[k][ty * 4];
            *(float4*)&b[0]  = *(const float4*)&Bs[k][tx * 8];
            *(float4*)&b[4]  = *(const float4*)&Bs[k][tx * 8 + 4];
#pragma unroll
            for (int i = 0; i < 4; ++i)
#pragma unroll
                for (int j = 0; j < 8; ++j)
                    acc[i][j] = fmaf(a[i], b[j], acc[i][j]);
        }
        __syncthreads();
    }
#pragma unroll
    for (int i = 0; i < 4; ++i) {
        int gr = m0 + ty * 4 + i;
        if (gr >= NNODE) continue;
        int sid = shape_id[gr], cid = color_id[gr];
        float p = pos[gr];
#pragma unroll
        for (int j = 0; j < 8; ++j) {
            int h = tx * 8 + j;
            float v = acc[i][j] + rootTab[sid * 128 + h] + rootTab[(16 + cid) * 128 + h]
                    + p * rootTab[32 * 128 + h] + bias[h];
            Cout[(size_t)gr * 512 + 384 + h] = fmaxf(v, 0.f);
        }
    }
}

// ---------------- layer-2 GEMM: MFMA bf16x3 split (fp32-accurate) ----------------
// Block tile 128(M)x128(N), BK=32, 4 waves in 2x2 grid, 64x64 per wave.
// A (=A2 [N][512] fp32) converted hi/lo on stage; B pre-split bf16 [128][512].
__global__ __launch_bounds__(256) void gemm2_mfma_kernel(
    const float* __restrict__ A,
    const short* __restrict__ Bt_hi, const short* __restrict__ Bt_lo,
    const float* __restrict__ bias,
    float* __restrict__ x2) {
    __shared__ short Ah[4][128][8];
    __shared__ short Al[4][128][8];
    __shared__ short Bh[4][128][8];
    __shared__ short Bl[4][128][8];
    const int t    = threadIdx.x;
    const int lane = t & 63;
    const int w    = t >> 6;
    const int wm   = w >> 1, wn = w & 1;
    const int bm0  = blockIdx.x * 128;
    const int lr   = lane & 15, lk = lane >> 4;
    f32x4 acc[4][4] = {};
    for (int kt = 0; kt < K2; kt += 32) {
        __syncthreads();
        // stage A: 128 rows x 32 k fp32 -> hi/lo bf16 in [kb][row][8]
#pragma unroll
        for (int p = 0; p < 4; ++p) {
            int idx = p * 256 + t;          // 0..1023
            int row = idx >> 3;             // 0..127
            int kq  = (idx & 7) * 4;        // 0..28
            int gr  = bm0 + row;
            float4 v = make_float4(0.f, 0.f, 0.f, 0.f);
            if (gr < NNODE) v = *(const float4*)&A[(size_t)gr * K2 + kt + kq];
            vshort4 h4, l4;
            float* vp = &v.x;
#pragma unroll
            for (int i = 0; i < 4; ++i) { short hh, ll; split_bf16(vp[i], hh, ll); h4[i] = hh; l4[i] = ll; }
            int kb = kq >> 3, j0 = kq & 7;
            *(vshort4*)&Ah[kb][row][j0] = h4;
            *(vshort4*)&Al[kb][row][j0] = l4;
        }
        // stage B: copy pre-split rows
#pragma unroll
        for (int p = 0; p < 2; ++p) {
            int idx = p * 256 + t;          // 0..511
            int n = idx >> 2, kb = idx & 3;
            *(vshort8*)&Bh[kb][n][0] = *(const vshort8*)&Bt_hi[(size_t)n * K2 + kt + kb * 8];
            *(vshort8*)&Bl[kb][n][0] = *(const vshort8*)&Bt_lo[(size_t)n * K2 + kt + kb * 8];
        }
        __syncthreads();
        vshort8 af_h[4], af_l[4], bf_h[4], bf_l[4];
#pragma unroll
        for (int f = 0; f < 4; ++f) {
            af_h[f] = *(const vshort8*)&Ah[lk][wm * 64 + f * 16 + lr][0];
            af_l[f] = *(const vshort8*)&Al[lk][wm * 64 + f * 16 + lr][0];
            bf_h[f] = *(const vshort8*)&Bh[lk][wn * 64 + f * 16 + lr][0];
            bf_l[f] = *(const vshort8*)&Bl[lk][wn * 64 + f * 16 + lr][0];
        }
#pragma unroll
        for (int mf = 0; mf < 4; ++mf)
#pragma unroll
            for (int nf = 0; nf < 4; ++nf) {
                acc[mf][nf] = __builtin_amdgcn_mfma_f32_16x16x32_bf16(af_h[mf], bf_h[nf], acc[mf][nf], 0, 0, 0);
                acc[mf][nf] = __builtin_amdgcn_mfma_f32_16x16x32_bf16(af_l[mf], bf_h[nf], acc[mf][nf], 0, 0, 0);
                acc[mf][nf] = __builtin_amdgcn_mfma_f32_16x16x32_bf16(af_h[mf], bf_l[nf], acc[mf][nf], 0, 0, 0);
            }
    }
    // epilogue: C[m][n], row=(lane>>4)*4+r, col=lane&15 within frag
#pragma unroll
    for (int mf = 0; mf < 4; ++mf) {
        int mb = bm0 + wm * 64 + mf * 16 + (lane >> 4) * 4;
#pragma unroll
        for (int nf = 0; nf < 4; ++nf) {
            int n = wn * 64 + nf * 16 + lr;
            float bn = bias[n];
#pragma unroll
            for (int r = 0; r < 4; ++r) {
                int gm = mb + r;
                if (gm < NNODE)
                    x2[(size_t)gm * HIDD + n] = fmaxf(acc[mf][nf][r] + bn, 0.f);
            }
        }
    }
}

// ---------------- pooling (batch sorted -> run-length reduce), 64 nodes/block ----------------
__global__ void pool_kernel(const float* __restrict__ x2, const int* __restrict__ batch,
                            float* __restrict__ pooled, float* __restrict__ cntg) {
    const int CH = 64;
    int h  = threadIdx.x; // 128
    int n0 = blockIdx.x * CH;
    if (n0 >= NNODE) return;
    int n1 = min(n0 + CH, NNODE);
    int cur = batch[n0];
    float acc = 0.f;
    int run = 0;
    for (int n = n0; n < n1; ++n) {
        int g = batch[n];
        if (g != cur) {
            atomicAdd(&pooled[cur * 128 + h], acc);
            if (h == 0) atomicAdd(&cntg[cur], (float)run);
            acc = 0.f; run = 0; cur = g;
        }
        acc += x2[(size_t)n * 128 + h];
        ++run;
    }
    atomicAdd(&pooled[cur * 128 + h], acc);
    if (h == 0) atomicAdd(&cntg[cur], (float)run);
}

__global__ void final_kernel(const float* __restrict__ pooled, const float* __restrict__ cntg,
                             const float* __restrict__ lin_w, const float* __restrict__ lin_b,
                             float* __restrict__ out) {
    int idx = blockIdx.x * blockDim.x + threadIdx.x;
    if (idx >= GNUM * 4) return;
    int g = idx >> 2, c = idx & 3;
    float dot = 0.f;
    for (int k = 0; k < 128; ++k) dot += pooled[g * 128 + k] * lin_w[k * 4 + c];
    out[idx] = dot / fmaxf(cntg[g], 1.f) + lin_b[c];
}

// ---------------- launch ----------------
extern "C" void kernel_launch(void* const* d_in, const int* in_sizes, int n_in,
                              void* d_out, int out_size, void* d_ws, size_t ws_size,
                              hipStream_t stream) {
    const float* pos      = (const float*)d_in[0];
    const int*   shape_id = (const int*)d_in[1];
    const int*   color_id = (const int*)d_in[2];
    const int*   ei       = (const int*)d_in[3];
    const int*   et       = (const int*)d_in[4];
    const int*   batch    = (const int*)d_in[5];
    const float* shape_w  = (const float*)d_in[6];
    const float* color_w  = (const float*)d_in[7];
    const float* W1       = (const float*)d_in[8];
    const float* root1    = (const float*)d_in[9];
    const float* b1       = (const float*)d_in[10];
    const float* W2       = (const float*)d_in[11];
    const float* root2    = (const float*)d_in[12];
    const float* b2       = (const float*)d_in[13];
    const float* lin_w    = (const float*)d_in[14];
    const float* lin_b    = (const float*)d_in[15];
    float* out = (float*)d_out;

    char* p = (char*)d_ws;
    auto alloc = [&](size_t bytes) { char* r = p; p += (bytes + 255) & ~(size_t)255; return r; };
    int*   cnt     = (int*)alloc((size_t)NNODE * 3 * 4);
    float* A1      = (float*)alloc((size_t)NNODE * K1 * 4);
    float* rcntBuf = (float*)alloc((size_t)NNODE * 4 * 4);
    float* A2      = (float*)alloc((size_t)NNODE * 512 * 4);
    float* x2      = (float*)alloc((size_t)NNODE * 128 * 4);
    float* B1eff   = (float*)alloc((size_t)K1 * 128 * 4);
    float* rootTab = (float*)alloc((size_t)33 * 128 * 4);
    short* Bt_hi   = (short*)alloc((size_t)128 * K2 * 2);
    short* Bt_lo   = (short*)alloc((size_t)128 * K2 * 2);
    float* pooled  = (float*)alloc((size_t)GNUM * 128 * 4);
    float* cntg    = (float*)alloc((size_t)GNUM * 4);
    // CSR temporaries alias into x2 (all consumed before gemm2 writes x2)
    char* xb = (char*)x2;
    int* sorted     = (int*)(xb);                       // E ints = 2.56 MB
    int* offs       = (int*)(xb + 2600960);             // NNODE+1 ints
    int* cursor     = (int*)(xb + 2900992);             // NNODE ints
    int* partial    = (int*)(xb + 3200000);             // NB ints
    int* partialPre = (int*)(xb + 3210240);             // NB ints

    hipMemsetAsync(cnt,    0, (size_t)NNODE * 3 * 4, stream);
    hipMemsetAsync(pooled, 0, (size_t)GNUM * 128 * 4, stream);
    hipMemsetAsync(cntg,   0, (size_t)GNUM * 4, stream);

    build_tabs_kernel<<<(4 * 33 * 128 + 255) / 256, 256, 0, stream>>>(
        shape_w, color_w, W1, root1, B1eff, rootTab);
    build_B2t_kernel<<<(K2 * 128 + 255) / 256, 256, 0, stream>>>(W2, root2, Bt_hi, Bt_lo);

    count_kernel<<<(NEDGE + 255) / 256, 256, 0, stream>>>(ei, et, cnt);
    scan_partial_kernel<<<NB, 256, 0, stream>>>(cnt, partial);
    scan_mid_kernel<<<1, 256, 0, stream>>>(partial, partialPre, offs);
    scan_final_kernel<<<NB, 256, 0, stream>>>(cnt, partialPre, offs, cursor);
    fill_kernel<<<(NEDGE + 255) / 256, 256, 0, stream>>>(ei, et, cursor, sorted);
    rcnt_kernel<<<(NNODE + 255) / 256, 256, 0, stream>>>(cnt, rcntBuf);

    hist1_kernel<<<NNODE, 64, 0, stream>>>(offs, sorted, shape_id, color_id, pos, A1);

    gemm1_kernel<<<(NNODE + 63) / 64, 256, 0, stream>>>(
        A1, B1eff, rcntBuf, shape_id, color_id, pos, rootTab, b1, A2);

    aggregate_kernel<<<NNODE, 128, 0, stream>>>(offs, sorted, rcntBuf, A2);

    gemm2_mfma_kernel<<<(NNODE + 127) / 128, 256, 0, stream>>>(
        A2, Bt_hi, Bt_lo, b2, x2);

    pool_kernel<<<(NNODE + 63) / 64, 128, 0, stream>>>(x2, batch, pooled, cntg);

    final_kernel<<<(GNUM * 4 + 255) / 256, 256, 0, stream>>>(
        pooled, cntg, lin_w, lin_b, out);
}